// Round 4
// baseline (1353.622 us; speedup 1.0000x reference)
//
#include <hip/hip_runtime.h>

// LSTM_8650064134553 : 2-layer stacked LSTM, B=32768, D=128, H=64, 32 steps.
// Round 5 = round 4 (fc folded into layer0, K=128 recurrence, no-unroll t-loop)
// + LDS-staged coalesced output stores.
//   Evidence: round0 (wave-contiguous stores) had WRITE=1.0x ideal and
//   FETCH=12MB (weights fully L2-resident); rounds 1-3 (16-lane x 128B
//   fragment stores) had WRITE=2.1x and FETCH=2.1-2.7GB. The fragmented
//   C-fragment store pattern causes partial-granule write amplification and
//   L2 churn that evicts the 288KB/step weight set. Fix: stage y in LDS,
//   store flat thread-linear float4 (1KB contiguous per wave instruction).

#define B_      32768
#define D_      128
#define H_      64
#define NSTEP_  32
#define ROWS_   64
#define NTHR_   256
#define NBLK_   (B_ / ROWS_)   // 512 blocks -> 2 blocks/CU

typedef __attribute__((ext_vector_type(8))) short  short8v;  // 8 bf16
typedef __attribute__((ext_vector_type(4))) float  float4v;  // mfma acc / f32x4
typedef __attribute__((ext_vector_type(2))) float  float2v;

// ws layout (ushort units). Total 425984 B + 1KB fused bias.
#define W0X_H 0        // t=0 layer0 (x-part of Wih0), 16n*4kt*64*8
#define W0X_L 32768
#define W0F_H 65536    // folded layer0: k<64 = Wih0@Wfc, k>=64 = Whh0
#define W0F_L 98304
#define W1_H  131072   // layer1: k<64 = Wih1 (h0), k>=64 = Whh1 (h1)
#define W1_L  163840
#define WF_H  196608   // fc, adjacent-col pack, 8n*2kt*64*8
#define WF_L  204800
#define B0P_BYTE 425984  // float[256] fused layer0 bias

// act planes: [64 rows][128 bf16 cols] = 256 B rows; cols [0..63]=h1,[64..127]=h0
// (at t=0 the 128 cols hold x). XOR swizzle vs stride-256 bank aliasing.
#define SWZ(row, bytecol) ((row) * 256 + ((bytecol) ^ (((row) & 7) << 4)))

__device__ __forceinline__ ushort f2bf(float f) {
  uint u = __float_as_uint(f);
  u += 0x7fffu + ((u >> 16) & 1u);      // RNE
  return (ushort)(u >> 16);
}
__device__ __forceinline__ float bf2f(ushort h) {
  return __uint_as_float((uint)h << 16);
}
__device__ __forceinline__ float fsig(float x) {
  float e = __builtin_amdgcn_exp2f(-1.44269504088896f * x);
  return __builtin_amdgcn_rcpf(1.0f + e);
}
__device__ __forceinline__ float ftanh(float x) {
  float e = __builtin_amdgcn_exp2f(2.88539008177793f * x);
  return 1.0f - 2.0f * __builtin_amdgcn_rcpf(e + 1.0f);
}

// B-fragment (16x16x32): lane l supplies B[k][n], n=l&15, k=(l>>4)*8+e.
// Layer N-tile perm: tile n -> orig col (n&3)*64 + (n>>2)*16 + (l&15).
// fc N-tile perm: tile n -> col (n>>1)*32 + 2*(l&15) + (n&1).
__global__ void prep_w(const float* __restrict__ Wih0,
                       const float* __restrict__ Whh0,
                       const float* __restrict__ b0,
                       const float* __restrict__ Wih1,
                       const float* __restrict__ Whh1,
                       const float* __restrict__ Wfc,
                       const float* __restrict__ bfc,
                       ushort* __restrict__ ws) {
  int idx = blockIdx.x * blockDim.x + threadIdx.x;
  int np  = gridDim.x * blockDim.x;
  // W0X: t=0 layer0, gates = x @ Wih0^T  (K=128 over x)
  for (int i = idx; i < 32768; i += np) {
    int e = i & 7, l = (i >> 3) & 63, r = i >> 9;
    int kt = r & 3, n = r >> 2;
    int col = (n & 3) * 64 + (n >> 2) * 16 + (l & 15);
    int k   = kt * 32 + (l >> 4) * 8 + e;
    float v = Wih0[col * D_ + k];
    ushort hi = f2bf(v);
    ws[W0X_H + i] = hi;
    ws[W0X_L + i] = f2bf(v - bf2f(hi));
  }
  // W0F: folded layer0, input [h1 | h0]
  for (int i = idx; i < 32768; i += np) {
    int e = i & 7, l = (i >> 3) & 63, r = i >> 9;
    int kt = r & 3, n = r >> 2;
    int col = (n & 3) * 64 + (n >> 2) * 16 + (l & 15);
    int k   = kt * 32 + (l >> 4) * 8 + e;
    float v;
    if (k < 64) {               // (Wih0 @ Wfc)[col][k]
      float s = 0.f;
      for (int d = 0; d < D_; ++d)
        s = fmaf(Wih0[col * D_ + d], Wfc[d * H_ + k], s);
      v = s;
    } else {
      v = Whh0[col * H_ + (k - 64)];
    }
    ushort hi = f2bf(v);
    ws[W0F_H + i] = hi;
    ws[W0F_L + i] = f2bf(v - bf2f(hi));
  }
  // W1: layer1, input [h0 | h1]
  for (int i = idx; i < 32768; i += np) {
    int e = i & 7, l = (i >> 3) & 63, r = i >> 9;
    int kt = r & 3, n = r >> 2;
    int col = (n & 3) * 64 + (n >> 2) * 16 + (l & 15);
    int k   = kt * 32 + (l >> 4) * 8 + e;
    float v = (k < 64) ? Wih1[col * H_ + k] : Whh1[col * H_ + (k - 64)];
    ushort hi = f2bf(v);
    ws[W1_H + i] = hi;
    ws[W1_L + i] = f2bf(v - bf2f(hi));
  }
  // WF: fc (output y only), K=64 over h1
  for (int i = idx; i < 8192; i += np) {
    int e = i & 7, l = (i >> 3) & 63, r = i >> 9;
    int kt = r & 1, n = r >> 1;
    int col = (n >> 1) * 32 + 2 * (l & 15) + (n & 1);
    int k   = kt * 32 + (l >> 4) * 8 + e;
    float v = Wfc[col * H_ + k];
    ushort hi = f2bf(v);
    ws[WF_H + i] = hi;
    ws[WF_L + i] = f2bf(v - bf2f(hi));
  }
  // b0p = b0 + Wih0 @ bfc
  float* b0p = (float*)((char*)ws + B0P_BYTE);
  for (int i = idx; i < 256; i += np) {
    float s = b0[i];
    for (int d = 0; d < D_; ++d) s = fmaf(Wih0[i * D_ + d], bfc[d], s);
    b0p[i] = s;
  }
}

#define LOAD_ACT(base_bytecol)                                \
  _Pragma("unroll") for (int mt = 0; mt < 4; ++mt) {          \
    int row_ = mt * 16 + c16;                                 \
    int off_ = SWZ(row_, (base_bytecol));                     \
    ah[mt] = *(const short8v*)((char*)act_h + off_);          \
    al[mt] = *(const short8v*)((char*)act_l + off_);          \
  }

#define MFMA3(BH, BL)                                         \
  _Pragma("unroll") for (int q = 0; q < 4; ++q)               \
  _Pragma("unroll") for (int mt = 0; mt < 4; ++mt) {          \
    acc[q][mt] = __builtin_amdgcn_mfma_f32_16x16x32_bf16(ah[mt], (BH)[q], acc[q][mt], 0, 0, 0); \
    acc[q][mt] = __builtin_amdgcn_mfma_f32_16x16x32_bf16(al[mt], (BH)[q], acc[q][mt], 0, 0, 0); \
    acc[q][mt] = __builtin_amdgcn_mfma_f32_16x16x32_bf16(ah[mt], (BL)[q], acc[q][mt], 0, 0, 0); \
  }

// phase-1 GEMM: reads act cols 0..127 with weight plane (BH,BL), K=128
#define GEMM_P1(BH, BL)                                       \
  _Pragma("unroll") for (int kt = 0; kt < 4; ++kt) {          \
    LOAD_ACT((kt * 32 + lq * 8) * 2);                         \
    short8v bh[4], bl[4];                                     \
    _Pragma("unroll") for (int q = 0; q < 4; ++q) {           \
      int idx_ = ((cg * 4 + q) * 4 + kt) * 64 + l;            \
      bh[q] = (BH)[idx_];  bl[q] = (BL)[idx_];                \
    }                                                         \
    MFMA3(bh, bl);                                            \
  }

__device__ __forceinline__ void lstm_ep(float4v (&acc)[4][4], float (&cs)[16],
                                        ushort* act_h, ushort* act_l,
                                        int colbase, int ucol, int lq,
                                        float bi, float bf, float bg, float bo) {
#pragma unroll
  for (int mt = 0; mt < 4; ++mt)
#pragma unroll
    for (int j = 0; j < 4; ++j) {
      float ig = fsig (acc[0][mt][j] + bi);
      float fg = fsig (acc[1][mt][j] + bf);
      float gg = ftanh(acc[2][mt][j] + bg);
      float og = fsig (acc[3][mt][j] + bo);
      float cn = fmaf(fg, cs[mt * 4 + j], ig * gg);
      cs[mt * 4 + j] = cn;
      float h = og * ftanh(cn);
      ushort hh = f2bf(h);
      ushort hl = f2bf(h - bf2f(hh));
      int row = mt * 16 + lq * 4 + j;
      int off = SWZ(row, (colbase + ucol) * 2);
      *(ushort*)((char*)act_h + off) = hh;
      *(ushort*)((char*)act_l + off) = hl;
    }
}

__global__ __launch_bounds__(NTHR_, 2)
void lstm_fused(const float* __restrict__ x,
                const float* __restrict__ b0,
                const float* __restrict__ b1,
                const float* __restrict__ bfc,
                const ushort* __restrict__ ws,
                float* __restrict__ out) {
  __shared__ __align__(16) ushort s_act_h[ROWS_ * 128];   // 16 KB
  __shared__ __align__(16) ushort s_act_l[ROWS_ * 128];   // 16 KB
  __shared__ __align__(16) float  y_st[ROWS_ * D_];       // 32 KB (total 64 KB)
  ushort* act_h = &s_act_h[0];
  ushort* act_l = &s_act_l[0];

  const int tid  = threadIdx.x;
  const int l    = tid & 63;
  const int cg   = tid >> 6;       // wave id = cell group (16 cells)
  const int c16  = l & 15;
  const int lq   = l >> 4;
  const int row0 = blockIdx.x * ROWS_;

  const short8v* W0Xh = (const short8v*)(ws + W0X_H);
  const short8v* W0Xl = (const short8v*)(ws + W0X_L);
  const short8v* W0Fh = (const short8v*)(ws + W0F_H);
  const short8v* W0Fl = (const short8v*)(ws + W0F_L);
  const short8v* W1h  = (const short8v*)(ws + W1_H);
  const short8v* W1l  = (const short8v*)(ws + W1_L);
  const short8v* WFh  = (const short8v*)(ws + WF_H);
  const short8v* WFl  = (const short8v*)(ws + WF_L);
  const float*   b0p  = (const float*)((const char*)ws + B0P_BYTE);

  const int ucol = cg * 16 + c16;  // this lane's cell 0..63
  const float bi0x = b0[ucol],  bf0x = b0[64 + ucol],  bg0x = b0[128 + ucol],  bo0x = b0[192 + ucol];
  const float bi0f = b0p[ucol], bf0f = b0p[64 + ucol], bg0f = b0p[128 + ucol], bo0f = b0p[192 + ucol];
  const float bi1 = b1[ucol], bf1 = b1[64 + ucol], bg1 = b1[128 + ucol], bo1 = b1[192 + ucol];
  const int coly0 = cg * 32 + 2 * c16;     // fc output cols (adjacent pair)
  const float by0 = bfc[coly0], by1 = bfc[coly0 + 1];

  float c0s[16], c1s[16];
#pragma unroll
  for (int i = 0; i < 16; ++i) { c0s[i] = 0.f; c1s[i] = 0.f; }

  // init: x (hi/lo) -> act cols 0..127
  for (int i = tid; i < ROWS_ * D_; i += NTHR_) {
    int row = i >> 7, col = i & 127;
    float v = x[(size_t)(row0 + row) * D_ + col];
    ushort hh = f2bf(v);
    ushort hl = f2bf(v - bf2f(hh));
    int off = SWZ(row, col * 2);
    *(ushort*)((char*)act_h + off) = hh;
    *(ushort*)((char*)act_l + off) = hl;
  }
  __syncthreads();

  const float4v zf = {0.f, 0.f, 0.f, 0.f};
  short8v ah[4], al[4];
  float4v acc[4][4];

  // ===================== t = 0 (input = x) =====================
  {
#pragma unroll
    for (int q = 0; q < 4; ++q)
#pragma unroll
      for (int mt = 0; mt < 4; ++mt) acc[q][mt] = zf;
    GEMM_P1(W0Xh, W0Xl);               // gates0 = x @ Wih0^T (h0=0)
    __syncthreads();
    lstm_ep(acc, c0s, act_h, act_l, 64, ucol, lq, bi0x, bf0x, bg0x, bo0x);
    __syncthreads();

    // layer1 t0: gates = h0 @ Wih1^T only (h1=0): kt 0..1 (act cols 64..127)
#pragma unroll
    for (int q = 0; q < 4; ++q)
#pragma unroll
      for (int mt = 0; mt < 4; ++mt) acc[q][mt] = zf;
#pragma unroll
    for (int kt = 0; kt < 2; ++kt) {
      LOAD_ACT((64 + kt * 32 + lq * 8) * 2);
      short8v bh[4], bl[4];
#pragma unroll
      for (int q = 0; q < 4; ++q) {
        int idx_ = ((cg * 4 + q) * 4 + kt) * 64 + l;
        bh[q] = W1h[idx_];  bl[q] = W1l[idx_];
      }
      MFMA3(bh, bl);
    }
    __syncthreads();
    lstm_ep(acc, c1s, act_h, act_l, 0, ucol, lq, bi1, bf1, bg1, bo1);
    __syncthreads();
  }

  // ===================== t = 1 .. 31 (uniform, NOT unrolled) =====================
#pragma unroll 1
  for (int t = 1; t < NSTEP_; ++t) {
    // P1: gates0 = [h1 | h0] @ W0'  (folded; cols 0..127)
#pragma unroll
    for (int q = 0; q < 4; ++q)
#pragma unroll
      for (int mt = 0; mt < 4; ++mt) acc[q][mt] = zf;
    GEMM_P1(W0Fh, W0Fl);
    __syncthreads();
    lstm_ep(acc, c0s, act_h, act_l, 64, ucol, lq, bi0f, bf0f, bg0f, bo0f);
    __syncthreads();

    // P2: gates1 = [h0 | h1] @ W1 ; fc y_{t-1} on the h1 k-tiles (kt>=2)
    float4v af[2][4];
#pragma unroll
    for (int q = 0; q < 4; ++q)
#pragma unroll
      for (int mt = 0; mt < 4; ++mt) acc[q][mt] = zf;
#pragma unroll
    for (int nq = 0; nq < 2; ++nq)
#pragma unroll
      for (int mt = 0; mt < 4; ++mt) af[nq][mt] = zf;

#pragma unroll
    for (int kt = 0; kt < 4; ++kt) {
      const int cb = (kt < 2) ? (64 + kt * 32) : ((kt - 2) * 32);
      LOAD_ACT((cb + lq * 8) * 2);
      short8v bh[4], bl[4];
#pragma unroll
      for (int q = 0; q < 4; ++q) {
        int idx_ = ((cg * 4 + q) * 4 + kt) * 64 + l;
        bh[q] = W1h[idx_];  bl[q] = W1l[idx_];
      }
      MFMA3(bh, bl);
      if (kt >= 2) {                      // same A frags = h1_{t-1}
        const int ktf = kt - 2;
        short8v fbh[2], fbl[2];
#pragma unroll
        for (int nq = 0; nq < 2; ++nq) {
          int idx_ = ((cg * 2 + nq) * 2 + ktf) * 64 + l;
          fbh[nq] = WFh[idx_];  fbl[nq] = WFl[idx_];
        }
#pragma unroll
        for (int nq = 0; nq < 2; ++nq)
#pragma unroll
          for (int mt = 0; mt < 4; ++mt) {
            af[nq][mt] = __builtin_amdgcn_mfma_f32_16x16x32_bf16(ah[mt], fbh[nq], af[nq][mt], 0, 0, 0);
            af[nq][mt] = __builtin_amdgcn_mfma_f32_16x16x32_bf16(al[mt], fbh[nq], af[nq][mt], 0, 0, 0);
            af[nq][mt] = __builtin_amdgcn_mfma_f32_16x16x32_bf16(ah[mt], fbl[nq], af[nq][mt], 0, 0, 0);
          }
      }
    }
    __syncthreads();
    lstm_ep(acc, c1s, act_h, act_l, 0, ucol, lq, bi1, bf1, bg1, bo1);

    // stage y_{t-1} (C-fragment layout) into LDS
#pragma unroll
    for (int mt = 0; mt < 4; ++mt)
#pragma unroll
      for (int j = 0; j < 4; ++j) {
        int row = mt * 16 + lq * 4 + j;
        float2v yv = {af[0][mt][j] + by0, af[1][mt][j] + by1};
        *(float2v*)&y_st[row * D_ + coly0] = yv;
      }
    __syncthreads();   // y_st complete; act (h1) complete for next P1

    // coalesced store: flat float4, 64 lanes x 16B = 1KB contiguous / instr
    const size_t obase = (size_t)t * (B_ * D_) + (size_t)row0 * D_;
#pragma unroll
    for (int i = 0; i < 8; ++i) {
      int f4  = i * NTHR_ + tid;
      int row = f4 >> 5;
      int c4  = (f4 & 31) * 4;
      float4v v = *(const float4v*)&y_st[row * D_ + c4];
      *(float4v*)(out + obase + (size_t)row * D_ + c4) = v;
    }
  }

  // ===================== tail: y_31 from h1_31 =====================
  {
    float4v af[2][4];
#pragma unroll
    for (int nq = 0; nq < 2; ++nq)
#pragma unroll
      for (int mt = 0; mt < 4; ++mt) af[nq][mt] = zf;
#pragma unroll
    for (int ktf = 0; ktf < 2; ++ktf) {
      LOAD_ACT((ktf * 32 + lq * 8) * 2);
      short8v fbh[2], fbl[2];
#pragma unroll
      for (int nq = 0; nq < 2; ++nq) {
        int idx_ = ((cg * 2 + nq) * 2 + ktf) * 64 + l;
        fbh[nq] = WFh[idx_];  fbl[nq] = WFl[idx_];
      }
#pragma unroll
      for (int nq = 0; nq < 2; ++nq)
#pragma unroll
        for (int mt = 0; mt < 4; ++mt) {
          af[nq][mt] = __builtin_amdgcn_mfma_f32_16x16x32_bf16(ah[mt], fbh[nq], af[nq][mt], 0, 0, 0);
          af[nq][mt] = __builtin_amdgcn_mfma_f32_16x16x32_bf16(al[mt], fbh[nq], af[nq][mt], 0, 0, 0);
          af[nq][mt] = __builtin_amdgcn_mfma_f32_16x16x32_bf16(ah[mt], fbl[nq], af[nq][mt], 0, 0, 0);
        }
    }
    __syncthreads();   // everyone done with step-31 y_st reads
#pragma unroll
    for (int mt = 0; mt < 4; ++mt)
#pragma unroll
      for (int j = 0; j < 4; ++j) {
        int row = mt * 16 + lq * 4 + j;
        float2v yv = {af[0][mt][j] + by0, af[1][mt][j] + by1};
        *(float2v*)&y_st[row * D_ + coly0] = yv;
      }
    __syncthreads();

    const size_t ob32 = (size_t)NSTEP_ * (B_ * D_) + (size_t)row0 * D_;
    const size_t obL  = (size_t)row0 * D_;           // y_last plane
#pragma unroll
    for (int i = 0; i < 8; ++i) {
      int f4  = i * NTHR_ + tid;
      int row = f4 >> 5;
      int c4  = (f4 & 31) * 4;
      float4v v = *(const float4v*)&y_st[row * D_ + c4];
      *(float4v*)(out + ob32 + (size_t)row * D_ + c4) = v;   // y_stack[31]
      *(float4v*)(out + obL  + (size_t)row * D_ + c4) = v;   // y_last
    }
  }
}

extern "C" void kernel_launch(void* const* d_in, const int* in_sizes, int n_in,
                              void* d_out, int out_size, void* d_ws, size_t ws_size,
                              hipStream_t stream) {
  const float* x    = (const float*)d_in[0];
  const float* Wih0 = (const float*)d_in[1];
  const float* Whh0 = (const float*)d_in[2];
  const float* b0   = (const float*)d_in[3];
  const float* Wih1 = (const float*)d_in[4];
  const float* Whh1 = (const float*)d_in[5];
  const float* b1   = (const float*)d_in[6];
  const float* Wfc  = (const float*)d_in[7];
  const float* bfc  = (const float*)d_in[8];
  ushort* ws  = (ushort*)d_ws;
  float* out  = (float*)d_out;

  prep_w<<<64, NTHR_, 0, stream>>>(Wih0, Whh0, b0, Wih1, Whh1, Wfc, bfc, ws);
  lstm_fused<<<NBLK_, NTHR_, 0, stream>>>(x, b0, b1, bfc, ws, out);
}